// Round 1
// baseline (2299.372 us; speedup 1.0000x reference)
//
#include <hip/hip_runtime.h>
#include <hip/hip_bf16.h>
#include <type_traits>

// TransformerBlockQuantum: B=4 S=2048 E=768 H=12 DK=64 FFN=3072 NQ=8
// Pipeline:
//   qkv = x@Wq/k/v^T + b         (bf16 MFMA GEMM -> qkv bf16 [8192,2304])
//   ctx = flash_attn(q,k,v,mask) (fp32 vector, -> ctx bf16 [8192,768])
//   attnp = ctx@wo^T + bo        (GEMM, fp32 out)
//   y = LN(x + attnp); meas = cos(y[:,:8]+theta)
//   h = relu(meas@w1^T + b1)     (bf16 [8192,3072])
//   ffnp = h@w2^T + b2           (GEMM, fp32 out)
//   out = LN(y + ffnp)

typedef __bf16 bf16_t;
typedef bf16_t bf16x4 __attribute__((ext_vector_type(4)));
typedef bf16_t bf16x8 __attribute__((ext_vector_type(8)));
typedef float floatx4 __attribute__((ext_vector_type(4)));

#define NTOK 8192

// ---------------- GEMM: C[M,N] = A[M,K] @ W[N,K]^T + bias ----------------
// BM=BN=128, BK=32, 256 threads = 4 waves (2x2), wave tile 64x64 via
// 4x4 frags of mfma_f32_16x16x32_bf16. LDS rows padded to 48 bf16 (96B)
// so ds_read_b128 stays 16B-aligned.
template<typename TA, typename TC>
__global__ __launch_bounds__(256)
void gemm_bt(const TA* __restrict__ A, const float* __restrict__ W,
             const float* __restrict__ bias, TC* __restrict__ C,
             int K, int lda, int ldw, int ldc)
{
    __shared__ bf16_t As[128][48];
    __shared__ bf16_t Bs[128][48];
    const int tid  = threadIdx.x;
    const int wave = tid >> 6;
    const int lane = tid & 63;
    const int wm = (wave >> 1) * 64;
    const int wn = (wave & 1) * 64;
    const int bm = blockIdx.y * 128;
    const int bn = blockIdx.x * 128;

    const int srow = tid >> 3;          // 0..31
    const int scol = (tid & 7) * 4;     // 0..28

    const int fr = lane & 15;           // fragment row/col within 16
    const int fk = (lane >> 4) * 8;     // k offset within 32

    floatx4 acc[4][4] = {};

    for (int k0 = 0; k0 < K; k0 += 32) {
        #pragma unroll
        for (int p = 0; p < 4; ++p) {
            const int r = srow + p * 32;
            bf16x4 va, vb;
            if constexpr (std::is_same<TA, float>::value) {
                const float4 f = *(const float4*)(A + (size_t)(bm + r) * lda + k0 + scol);
                va[0] = (bf16_t)f.x; va[1] = (bf16_t)f.y;
                va[2] = (bf16_t)f.z; va[3] = (bf16_t)f.w;
            } else {
                va = *(const bf16x4*)(A + (size_t)(bm + r) * lda + k0 + scol);
            }
            {
                const float4 f = *(const float4*)(W + (size_t)(bn + r) * ldw + k0 + scol);
                vb[0] = (bf16_t)f.x; vb[1] = (bf16_t)f.y;
                vb[2] = (bf16_t)f.z; vb[3] = (bf16_t)f.w;
            }
            *(bf16x4*)&As[r][scol] = va;
            *(bf16x4*)&Bs[r][scol] = vb;
        }
        __syncthreads();

        bf16x8 fa[4], fb[4];
        #pragma unroll
        for (int i = 0; i < 4; ++i) {
            fa[i] = *(const bf16x8*)&As[wm + i * 16 + fr][fk];
            fb[i] = *(const bf16x8*)&Bs[wn + i * 16 + fr][fk];
        }
        #pragma unroll
        for (int mi = 0; mi < 4; ++mi)
            #pragma unroll
            for (int ni = 0; ni < 4; ++ni)
                acc[mi][ni] = __builtin_amdgcn_mfma_f32_16x16x32_bf16(
                    fa[mi], fb[ni], acc[mi][ni], 0, 0, 0);
        __syncthreads();
    }

    const int fg = (lane >> 4) * 4;
    #pragma unroll
    for (int mi = 0; mi < 4; ++mi) {
        #pragma unroll
        for (int ni = 0; ni < 4; ++ni) {
            const int col = bn + wn + ni * 16 + fr;
            const float bv = bias[col];
            #pragma unroll
            for (int r = 0; r < 4; ++r) {
                const int row = bm + wm + mi * 16 + fg + r;
                C[(size_t)row * ldc + col] = (TC)(acc[mi][ni][r] + bv);
            }
        }
    }
}

// ---------------- flash attention, fp32 vector ----------------
// grid: (8 q-blocks, 48 bh). 256 threads, thread owns one query row.
// K/V tiles of 64 keys staged fp32 in LDS; online softmax in 16-key subtiles.
__global__ __launch_bounds__(256)
void attn_fp32(const bf16_t* __restrict__ qkv, const int* __restrict__ mask,
               bf16_t* __restrict__ ctx)
{
    const int bh = blockIdx.y;
    const int b = bh / 12, h = bh % 12;
    const int tid = threadIdx.x;
    const int qi  = blockIdx.x * 256 + tid;
    const int tok = b * 2048 + qi;

    __shared__ float Ks[64][64];
    __shared__ float Vs[64][64];
    __shared__ float maskv[64];

    // Q row, pre-scaled by 1/sqrt(64)
    float q[64];
    const bf16_t* qp = qkv + (size_t)tok * 2304 + h * 64;
    #pragma unroll
    for (int i = 0; i < 16; ++i) {
        bf16x4 v = *(const bf16x4*)(qp + i * 4);
        q[i*4+0] = (float)v[0] * 0.125f;
        q[i*4+1] = (float)v[1] * 0.125f;
        q[i*4+2] = (float)v[2] * 0.125f;
        q[i*4+3] = (float)v[3] * 0.125f;
    }

    float m = -1e30f, lsum = 0.f;
    float acc[64];
    #pragma unroll
    for (int i = 0; i < 64; ++i) acc[i] = 0.f;

    for (int kt = 0; kt < 32; ++kt) {
        __syncthreads();
        {   // stage: thread -> row tid>>2, 16 cols starting (tid&3)*16
            const int jr = tid >> 2;
            const int jc = (tid & 3) * 16;
            const int ktok = b * 2048 + kt * 64 + jr;
            const bf16_t* kp = qkv + (size_t)ktok * 2304 + 768  + h * 64 + jc;
            const bf16_t* vp = qkv + (size_t)ktok * 2304 + 1536 + h * 64 + jc;
            #pragma unroll
            for (int i = 0; i < 4; ++i) {
                bf16x4 kv = *(const bf16x4*)(kp + i * 4);
                bf16x4 vv = *(const bf16x4*)(vp + i * 4);
                float4 kf = { (float)kv[0], (float)kv[1], (float)kv[2], (float)kv[3] };
                float4 vf = { (float)vv[0], (float)vv[1], (float)vv[2], (float)vv[3] };
                *(float4*)&Ks[jr][jc + i * 4] = kf;
                *(float4*)&Vs[jr][jc + i * 4] = vf;
            }
            if (tid < 64)
                maskv[tid] = (mask[b * 2048 + kt * 64 + tid] == 0) ? -1.f : 1.f;
        }
        __syncthreads();

        #pragma unroll 1
        for (int sub = 0; sub < 4; ++sub) {
            float s[16];
            #pragma unroll
            for (int jj = 0; jj < 16; ++jj) {
                const int j = sub * 16 + jj;
                const float4* kr = (const float4*)&Ks[j][0];
                float acs = 0.f;
                #pragma unroll
                for (int i = 0; i < 16; ++i) {
                    const float4 kv = kr[i];
                    acs += q[i*4+0]*kv.x + q[i*4+1]*kv.y + q[i*4+2]*kv.z + q[i*4+3]*kv.w;
                }
                s[jj] = (maskv[j] < 0.f) ? -1e9f : acs;
            }
            float tm = s[0];
            #pragma unroll
            for (int jj = 1; jj < 16; ++jj) tm = fmaxf(tm, s[jj]);
            const float mn = fmaxf(m, tm);
            const float scale = __expf(m - mn);
            lsum *= scale;
            #pragma unroll
            for (int i = 0; i < 64; ++i) acc[i] *= scale;
            #pragma unroll
            for (int jj = 0; jj < 16; ++jj) {
                const float p = __expf(s[jj] - mn);
                lsum += p;
                const float4* vr = (const float4*)&Vs[sub * 16 + jj][0];
                #pragma unroll
                for (int i = 0; i < 16; ++i) {
                    const float4 vv = vr[i];
                    acc[i*4+0] += p * vv.x;
                    acc[i*4+1] += p * vv.y;
                    acc[i*4+2] += p * vv.z;
                    acc[i*4+3] += p * vv.w;
                }
            }
            m = mn;
        }
    }

    const float inv = 1.f / lsum;
    bf16_t* cp = ctx + (size_t)tok * 768 + h * 64;
    #pragma unroll
    for (int i = 0; i < 16; ++i) {
        bf16x4 o;
        o[0] = (bf16_t)(acc[i*4+0] * inv);
        o[1] = (bf16_t)(acc[i*4+1] * inv);
        o[2] = (bf16_t)(acc[i*4+2] * inv);
        o[3] = (bf16_t)(acc[i*4+3] * inv);
        *(bf16x4*)(cp + i * 4) = o;
    }
}

// ---------------- fused residual + LayerNorm (+ optional meas) ----------------
__global__ __launch_bounds__(256)
void ln_fuse(const float* __restrict__ xin, const float* __restrict__ proj,
             const float* __restrict__ g, const float* __restrict__ be,
             float* __restrict__ out,
             const float* __restrict__ theta, float* __restrict__ meas)
{
    const int row = blockIdx.x;
    const int tid = threadIdx.x;
    const size_t base = (size_t)row * 768;
    const float v0 = xin[base + tid]       + proj[base + tid];
    const float v1 = xin[base + tid + 256] + proj[base + tid + 256];
    const float v2 = xin[base + tid + 512] + proj[base + tid + 512];
    float s1 = v0 + v1 + v2;
    float s2 = v0*v0 + v1*v1 + v2*v2;
    #pragma unroll
    for (int mk = 32; mk >= 1; mk >>= 1) {
        s1 += __shfl_xor(s1, mk, 64);
        s2 += __shfl_xor(s2, mk, 64);
    }
    __shared__ float w1s[4], w2s[4];
    const int wave = tid >> 6;
    if ((tid & 63) == 0) { w1s[wave] = s1; w2s[wave] = s2; }
    __syncthreads();
    const float tot1 = w1s[0] + w1s[1] + w1s[2] + w1s[3];
    const float tot2 = w2s[0] + w2s[1] + w2s[2] + w2s[3];
    const float mu   = tot1 * (1.f / 768.f);
    const float var  = tot2 * (1.f / 768.f) - mu * mu;
    const float rinv = rsqrtf(var + 1e-5f);
    const float y0 = (v0 - mu) * rinv * g[tid] + be[tid];
    out[base + tid]       = y0;
    out[base + tid + 256] = (v1 - mu) * rinv * g[tid + 256] + be[tid + 256];
    out[base + tid + 512] = (v2 - mu) * rinv * g[tid + 512] + be[tid + 512];
    if (meas != nullptr && tid < 8)
        meas[row * 8 + tid] = cosf(y0 + theta[tid]);
}

// ---------------- quantum FFN stage 1: h = relu(meas@w1^T + b1), bf16 ----------------
__global__ __launch_bounds__(256)
void ffn1(const float* __restrict__ meas, const float* __restrict__ w1,
          const float* __restrict__ b1, bf16_t* __restrict__ h)
{
    const int row = blockIdx.x;
    __shared__ float ms[8];
    if (threadIdx.x < 8) ms[threadIdx.x] = meas[row * 8 + threadIdx.x];
    __syncthreads();
    #pragma unroll
    for (int i = 0; i < 12; ++i) {
        const int f = threadIdx.x + i * 256;
        const float4 wa = *(const float4*)(w1 + f * 8);
        const float4 wb = *(const float4*)(w1 + f * 8 + 4);
        float v = b1[f];
        v += ms[0]*wa.x + ms[1]*wa.y + ms[2]*wa.z + ms[3]*wa.w;
        v += ms[4]*wb.x + ms[5]*wb.y + ms[6]*wb.z + ms[7]*wb.w;
        h[(size_t)row * 3072 + f] = (bf16_t)fmaxf(v, 0.f);
    }
}

extern "C" void kernel_launch(void* const* d_in, const int* in_sizes, int n_in,
                              void* d_out, int out_size, void* d_ws, size_t ws_size,
                              hipStream_t stream)
{
    const float* x     = (const float*)d_in[0];
    const int*   mask  = (const int*)d_in[1];
    const float* wq    = (const float*)d_in[2];
    const float* bq    = (const float*)d_in[3];
    const float* wk    = (const float*)d_in[4];
    const float* bk    = (const float*)d_in[5];
    const float* wv    = (const float*)d_in[6];
    const float* bv    = (const float*)d_in[7];
    const float* wo    = (const float*)d_in[8];
    const float* bo    = (const float*)d_in[9];
    const float* g1    = (const float*)d_in[10];
    const float* be1   = (const float*)d_in[11];
    const float* g2    = (const float*)d_in[12];
    const float* be2   = (const float*)d_in[13];
    const float* theta = (const float*)d_in[14];
    const float* w1    = (const float*)d_in[15];
    const float* b1    = (const float*)d_in[16];
    const float* w2    = (const float*)d_in[17];
    const float* b2    = (const float*)d_in[18];
    float* out = (float*)d_out;

    char* ws = (char*)d_ws;
    // layout (bytes): qkv bf16 [8192,2304] | ctx bf16 [8192,768] |
    // attnp f32 [8192,768] | y f32 [8192,768] | meas f32 [8192,8] | h bf16 [8192,3072]
    bf16_t* qkv   = (bf16_t*)(ws + 0);
    bf16_t* ctx   = (bf16_t*)(ws + 37748736);
    float*  attnp = (float*)(ws + 50331648);
    float*  y     = (float*)(ws + 75497472);
    float*  meas  = (float*)(ws + 100663296);
    bf16_t* h     = (bf16_t*)(ws + 100925440);
    float*  ffnp  = (float*)(ws + 0);   // aliases qkv (dead after attention)

    const dim3 blk(256);
    const dim3 g6(6, 64);   // N=768 tiles x M=8192 tiles

    gemm_bt<float, bf16_t><<<g6, blk, 0, stream>>>(x, wq, bq, qkv + 0,    768, 768, 768, 2304);
    gemm_bt<float, bf16_t><<<g6, blk, 0, stream>>>(x, wk, bk, qkv + 768,  768, 768, 768, 2304);
    gemm_bt<float, bf16_t><<<g6, blk, 0, stream>>>(x, wv, bv, qkv + 1536, 768, 768, 768, 2304);

    attn_fp32<<<dim3(8, 48), blk, 0, stream>>>(qkv, mask, ctx);

    gemm_bt<bf16_t, float><<<g6, blk, 0, stream>>>(ctx, wo, bo, attnp, 768, 768, 768, 768);

    ln_fuse<<<dim3(8192), blk, 0, stream>>>(x, attnp, g1, be1, y, theta, meas);

    ffn1<<<dim3(8192), blk, 0, stream>>>(meas, w1, b1, h);

    gemm_bt<bf16_t, float><<<g6, blk, 0, stream>>>(h, w2, b2, ffnp, 3072, 3072, 3072, 768);

    ln_fuse<<<dim3(8192), blk, 0, stream>>>(y, ffnp, g2, be2, out, nullptr, nullptr);
}

// Round 2
// 469.323 us; speedup vs baseline: 4.8993x; 4.8993x over previous
//
#include <hip/hip_runtime.h>
#include <hip/hip_bf16.h>
#include <type_traits>

// TransformerBlockQuantum: B=4 S=2048 E=768 H=12 DK=64 FFN=3072 NQ=8
//   qkv = x@Wq/k/v^T + b         (bf16 MFMA GEMM -> qkv bf16 [8192,2304])
//   ctx = flash_attn(q,k,v,mask) (bf16 MFMA flash -> ctx bf16 [8192,768])
//   attnp = ctx@wo^T + bo        (GEMM, fp32 out)
//   y = LN(x + attnp); meas = cos(y[:,:8]+theta)
//   h = relu(meas@w1^T + b1)     (bf16 [8192,3072])
//   ffnp = h@w2^T + b2           (GEMM, fp32 out)
//   out = LN(y + ffnp)

typedef __bf16 bf16_t;
typedef bf16_t bf16x4 __attribute__((ext_vector_type(4)));
typedef bf16_t bf16x8 __attribute__((ext_vector_type(8)));
typedef float floatx4 __attribute__((ext_vector_type(4)));

// ---------------- GEMM: C[M,N] = A[M,K] @ W[N,K]^T + bias ----------------
template<typename TA, typename TC>
__global__ __launch_bounds__(256)
void gemm_bt(const TA* __restrict__ A, const float* __restrict__ W,
             const float* __restrict__ bias, TC* __restrict__ C,
             int K, int lda, int ldw, int ldc)
{
    __shared__ bf16_t As[128][48];
    __shared__ bf16_t Bs[128][48];
    const int tid  = threadIdx.x;
    const int wave = tid >> 6;
    const int lane = tid & 63;
    const int wm = (wave >> 1) * 64;
    const int wn = (wave & 1) * 64;
    const int bm = blockIdx.y * 128;
    const int bn = blockIdx.x * 128;

    const int srow = tid >> 3;          // 0..31
    const int scol = (tid & 7) * 4;     // 0..28

    const int fr = lane & 15;
    const int fk = (lane >> 4) * 8;

    floatx4 acc[4][4] = {};

    for (int k0 = 0; k0 < K; k0 += 32) {
        #pragma unroll
        for (int p = 0; p < 4; ++p) {
            const int r = srow + p * 32;
            bf16x4 va, vb;
            if constexpr (std::is_same<TA, float>::value) {
                const float4 f = *(const float4*)(A + (size_t)(bm + r) * lda + k0 + scol);
                va[0] = (bf16_t)f.x; va[1] = (bf16_t)f.y;
                va[2] = (bf16_t)f.z; va[3] = (bf16_t)f.w;
            } else {
                va = *(const bf16x4*)(A + (size_t)(bm + r) * lda + k0 + scol);
            }
            {
                const float4 f = *(const float4*)(W + (size_t)(bn + r) * ldw + k0 + scol);
                vb[0] = (bf16_t)f.x; vb[1] = (bf16_t)f.y;
                vb[2] = (bf16_t)f.z; vb[3] = (bf16_t)f.w;
            }
            *(bf16x4*)&As[r][scol] = va;
            *(bf16x4*)&Bs[r][scol] = vb;
        }
        __syncthreads();

        bf16x8 fa[4], fb[4];
        #pragma unroll
        for (int i = 0; i < 4; ++i) {
            fa[i] = *(const bf16x8*)&As[wm + i * 16 + fr][fk];
            fb[i] = *(const bf16x8*)&Bs[wn + i * 16 + fr][fk];
        }
        #pragma unroll
        for (int mi = 0; mi < 4; ++mi)
            #pragma unroll
            for (int ni = 0; ni < 4; ++ni)
                acc[mi][ni] = __builtin_amdgcn_mfma_f32_16x16x32_bf16(
                    fa[mi], fb[ni], acc[mi][ni], 0, 0, 0);
        __syncthreads();
    }

    const int fg = (lane >> 4) * 4;
    #pragma unroll
    for (int mi = 0; mi < 4; ++mi) {
        #pragma unroll
        for (int ni = 0; ni < 4; ++ni) {
            const int col = bn + wn + ni * 16 + fr;
            const float bv = bias[col];
            #pragma unroll
            for (int r = 0; r < 4; ++r) {
                const int row = bm + wm + mi * 16 + fg + r;
                C[(size_t)row * ldc + col] = (TC)(acc[mi][ni][r] + bv);
            }
        }
    }
}

// ---------------- MFMA flash attention ----------------
// grid (16 q-blocks, 48 bh) x 256 threads. Block: 128 q-rows of one head;
// wave owns 32 q-rows. KV tiles of 64 keys in LDS (K row-major padded,
// V transposed). QK^T and PV via mfma_f32_16x16x32_bf16; online softmax
// in fp32; P re-laid out via per-wave LDS buffer.
__global__ __launch_bounds__(256)
void attn_mfma(const bf16_t* __restrict__ qkv, const int* __restrict__ mask,
               bf16_t* __restrict__ ctx)
{
    __shared__ bf16_t Ks[64][72];        // K[key][d], +8 pad (144B stride)
    __shared__ bf16_t Vt[64][72];        // V^T[d][key]
    __shared__ float  mb_s[64];
    __shared__ bf16_t Pl[4][32][72];     // per-wave P[q][key]

    const int bh = blockIdx.y;
    const int b = bh / 12, h = bh % 12;
    const int tid  = threadIdx.x;
    const int wave = tid >> 6;
    const int lane = tid & 63;
    const int g    = lane >> 4;          // 0..3
    const int fr   = lane & 15;          // 0..15
    const int qbase = blockIdx.x * 128 + wave * 32;

    // Q fragments (A-operand), pre-scaled by 1/sqrt(64) = 2^-3 (exact in bf16)
    bf16x8 qf[2][2];
    #pragma unroll
    for (int qt = 0; qt < 2; ++qt)
        #pragma unroll
        for (int s = 0; s < 2; ++s) {
            const size_t tok = (size_t)(b * 2048 + qbase + qt * 16 + fr);
            qf[qt][s] = *(const bf16x8*)(qkv + tok * 2304 + h * 64 + s * 32 + g * 8);
            #pragma unroll
            for (int j = 0; j < 8; ++j)
                qf[qt][s][j] = (bf16_t)((float)qf[qt][s][j] * 0.125f);
        }

    float m[2][4], l[2][4];
    floatx4 o[2][4] = {};
    #pragma unroll
    for (int qt = 0; qt < 2; ++qt)
        #pragma unroll
        for (int r = 0; r < 4; ++r) { m[qt][r] = -1e30f; l[qt][r] = 0.f; }

    const int skey = tid & 63;
    const int sgrp = tid >> 6;

    for (int kt = 0; kt < 32; ++kt) {
        __syncthreads();
        {   // stage K (row-major) and V (transposed)
            const size_t ktok = (size_t)(b * 2048 + kt * 64 + skey) * 2304 + h * 64;
            const bf16x8 k0 = *(const bf16x8*)(qkv + ktok + 768 + sgrp * 16);
            const bf16x8 k1 = *(const bf16x8*)(qkv + ktok + 768 + sgrp * 16 + 8);
            *(bf16x8*)&Ks[skey][sgrp * 16]     = k0;
            *(bf16x8*)&Ks[skey][sgrp * 16 + 8] = k1;
            const bf16x8 v0 = *(const bf16x8*)(qkv + ktok + 1536 + sgrp * 16);
            const bf16x8 v1 = *(const bf16x8*)(qkv + ktok + 1536 + sgrp * 16 + 8);
            #pragma unroll
            for (int j = 0; j < 8; ++j) {
                Vt[sgrp * 16 + j][skey]     = v0[j];
                Vt[sgrp * 16 + 8 + j][skey] = v1[j];
            }
            if (tid < 64)
                mb_s[tid] = (mask[b * 2048 + kt * 64 + tid] == 0) ? -1e9f : 0.f;
        }
        __syncthreads();

        // ---- QK^T ----
        floatx4 sacc[2][4] = {};
        #pragma unroll
        for (int s = 0; s < 2; ++s) {
            bf16x8 kf[4];
            #pragma unroll
            for (int ct = 0; ct < 4; ++ct)
                kf[ct] = *(const bf16x8*)&Ks[ct * 16 + fr][s * 32 + g * 8];
            #pragma unroll
            for (int qt = 0; qt < 2; ++qt)
                #pragma unroll
                for (int ct = 0; ct < 4; ++ct)
                    sacc[qt][ct] = __builtin_amdgcn_mfma_f32_16x16x32_bf16(
                        qf[qt][s], kf[ct], sacc[qt][ct], 0, 0, 0);
        }

        float mbv[4];
        #pragma unroll
        for (int ct = 0; ct < 4; ++ct) mbv[ct] = mb_s[ct * 16 + fr];

        // ---- online softmax (acc layout: col=key=fr, row=q=g*4+r) ----
        #pragma unroll
        for (int qt = 0; qt < 2; ++qt) {
            float sv[4][4];
            #pragma unroll
            for (int ct = 0; ct < 4; ++ct)
                #pragma unroll
                for (int r = 0; r < 4; ++r)
                    sv[ct][r] = sacc[qt][ct][r] + mbv[ct];
            float tm[4];
            #pragma unroll
            for (int r = 0; r < 4; ++r)
                tm[r] = fmaxf(fmaxf(sv[0][r], sv[1][r]), fmaxf(sv[2][r], sv[3][r]));
            #pragma unroll
            for (int mk = 1; mk < 16; mk <<= 1)
                #pragma unroll
                for (int r = 0; r < 4; ++r)
                    tm[r] = fmaxf(tm[r], __shfl_xor(tm[r], mk, 64));
            float ps[4] = {0.f, 0.f, 0.f, 0.f};
            #pragma unroll
            for (int r = 0; r < 4; ++r) {
                const float mn = fmaxf(m[qt][r], tm[r]);
                const float sc = __expf(m[qt][r] - mn);
                m[qt][r] = mn;
                l[qt][r] *= sc;
                #pragma unroll
                for (int dt = 0; dt < 4; ++dt) o[qt][dt][r] *= sc;
                #pragma unroll
                for (int ct = 0; ct < 4; ++ct) {
                    const float p = __expf(sv[ct][r] - mn);
                    ps[r] += p;
                    Pl[wave][qt * 16 + g * 4 + r][ct * 16 + fr] = (bf16_t)p;
                }
            }
            #pragma unroll
            for (int mk = 1; mk < 16; mk <<= 1)
                #pragma unroll
                for (int r = 0; r < 4; ++r)
                    ps[r] += __shfl_xor(ps[r], mk, 64);
            #pragma unroll
            for (int r = 0; r < 4; ++r) l[qt][r] += ps[r];
        }

        // ---- PV (wave-local Pl: no block barrier needed) ----
        #pragma unroll
        for (int st = 0; st < 2; ++st) {
            bf16x8 pf[2], vf[4];
            #pragma unroll
            for (int qt = 0; qt < 2; ++qt)
                pf[qt] = *(const bf16x8*)&Pl[wave][qt * 16 + fr][st * 32 + g * 8];
            #pragma unroll
            for (int dt = 0; dt < 4; ++dt)
                vf[dt] = *(const bf16x8*)&Vt[dt * 16 + fr][st * 32 + g * 8];
            #pragma unroll
            for (int qt = 0; qt < 2; ++qt)
                #pragma unroll
                for (int dt = 0; dt < 4; ++dt)
                    o[qt][dt] = __builtin_amdgcn_mfma_f32_16x16x32_bf16(
                        pf[qt], vf[dt], o[qt][dt], 0, 0, 0);
        }
    }

    // ---- epilogue ----
    #pragma unroll
    for (int qt = 0; qt < 2; ++qt) {
        float inv[4];
        #pragma unroll
        for (int r = 0; r < 4; ++r) inv[r] = 1.f / l[qt][r];
        #pragma unroll
        for (int dt = 0; dt < 4; ++dt)
            #pragma unroll
            for (int r = 0; r < 4; ++r) {
                const size_t row = (size_t)(b * 2048 + qbase + qt * 16 + g * 4 + r);
                ctx[row * 768 + h * 64 + dt * 16 + fr] = (bf16_t)(o[qt][dt][r] * inv[r]);
            }
    }
}

// ---------------- fused residual + LayerNorm (+ optional meas) ----------------
__global__ __launch_bounds__(256)
void ln_fuse(const float* __restrict__ xin, const float* __restrict__ proj,
             const float* __restrict__ g, const float* __restrict__ be,
             float* __restrict__ out,
             const float* __restrict__ theta, float* __restrict__ meas)
{
    const int row = blockIdx.x;
    const int tid = threadIdx.x;
    const size_t base = (size_t)row * 768;
    const float v0 = xin[base + tid]       + proj[base + tid];
    const float v1 = xin[base + tid + 256] + proj[base + tid + 256];
    const float v2 = xin[base + tid + 512] + proj[base + tid + 512];
    float s1 = v0 + v1 + v2;
    float s2 = v0*v0 + v1*v1 + v2*v2;
    #pragma unroll
    for (int mk = 32; mk >= 1; mk >>= 1) {
        s1 += __shfl_xor(s1, mk, 64);
        s2 += __shfl_xor(s2, mk, 64);
    }
    __shared__ float w1s[4], w2s[4];
    const int wave = tid >> 6;
    if ((tid & 63) == 0) { w1s[wave] = s1; w2s[wave] = s2; }
    __syncthreads();
    const float tot1 = w1s[0] + w1s[1] + w1s[2] + w1s[3];
    const float tot2 = w2s[0] + w2s[1] + w2s[2] + w2s[3];
    const float mu   = tot1 * (1.f / 768.f);
    const float var  = tot2 * (1.f / 768.f) - mu * mu;
    const float rinv = rsqrtf(var + 1e-5f);
    const float y0 = (v0 - mu) * rinv * g[tid] + be[tid];
    out[base + tid]       = y0;
    out[base + tid + 256] = (v1 - mu) * rinv * g[tid + 256] + be[tid + 256];
    out[base + tid + 512] = (v2 - mu) * rinv * g[tid + 512] + be[tid + 512];
    if (meas != nullptr && tid < 8)
        meas[row * 8 + tid] = cosf(y0 + theta[tid]);
}

// ---------------- quantum FFN stage 1 ----------------
__global__ __launch_bounds__(256)
void ffn1(const float* __restrict__ meas, const float* __restrict__ w1,
          const float* __restrict__ b1, bf16_t* __restrict__ h)
{
    const int row = blockIdx.x;
    __shared__ float ms[8];
    if (threadIdx.x < 8) ms[threadIdx.x] = meas[row * 8 + threadIdx.x];
    __syncthreads();
    #pragma unroll
    for (int i = 0; i < 12; ++i) {
        const int f = threadIdx.x + i * 256;
        const float4 wa = *(const float4*)(w1 + f * 8);
        const float4 wb = *(const float4*)(w1 + f * 8 + 4);
        float v = b1[f];
        v += ms[0]*wa.x + ms[1]*wa.y + ms[2]*wa.z + ms[3]*wa.w;
        v += ms[4]*wb.x + ms[5]*wb.y + ms[6]*wb.z + ms[7]*wb.w;
        h[(size_t)row * 3072 + f] = (bf16_t)fmaxf(v, 0.f);
    }
}

extern "C" void kernel_launch(void* const* d_in, const int* in_sizes, int n_in,
                              void* d_out, int out_size, void* d_ws, size_t ws_size,
                              hipStream_t stream)
{
    const float* x     = (const float*)d_in[0];
    const int*   mask  = (const int*)d_in[1];
    const float* wq    = (const float*)d_in[2];
    const float* bq    = (const float*)d_in[3];
    const float* wk    = (const float*)d_in[4];
    const float* bk    = (const float*)d_in[5];
    const float* wv    = (const float*)d_in[6];
    const float* bv    = (const float*)d_in[7];
    const float* wo    = (const float*)d_in[8];
    const float* bo    = (const float*)d_in[9];
    const float* g1    = (const float*)d_in[10];
    const float* be1   = (const float*)d_in[11];
    const float* g2    = (const float*)d_in[12];
    const float* be2   = (const float*)d_in[13];
    const float* theta = (const float*)d_in[14];
    const float* w1    = (const float*)d_in[15];
    const float* b1    = (const float*)d_in[16];
    const float* w2    = (const float*)d_in[17];
    const float* b2    = (const float*)d_in[18];
    float* out = (float*)d_out;

    char* ws = (char*)d_ws;
    bf16_t* qkv   = (bf16_t*)(ws + 0);
    bf16_t* ctx   = (bf16_t*)(ws + 37748736);
    float*  attnp = (float*)(ws + 50331648);
    float*  y     = (float*)(ws + 75497472);
    float*  meas  = (float*)(ws + 100663296);
    bf16_t* h     = (bf16_t*)(ws + 100925440);
    float*  ffnp  = (float*)(ws + 0);   // aliases qkv (dead after attention)

    const dim3 blk(256);
    const dim3 g6(6, 64);

    gemm_bt<float, bf16_t><<<g6, blk, 0, stream>>>(x, wq, bq, qkv + 0,    768, 768, 768, 2304);
    gemm_bt<float, bf16_t><<<g6, blk, 0, stream>>>(x, wk, bk, qkv + 768,  768, 768, 768, 2304);
    gemm_bt<float, bf16_t><<<g6, blk, 0, stream>>>(x, wv, bv, qkv + 1536, 768, 768, 768, 2304);

    attn_mfma<<<dim3(16, 48), blk, 0, stream>>>(qkv, mask, ctx);

    gemm_bt<bf16_t, float><<<g6, blk, 0, stream>>>(ctx, wo, bo, attnp, 768, 768, 768, 768);

    ln_fuse<<<dim3(8192), blk, 0, stream>>>(x, attnp, g1, be1, y, theta, meas);

    ffn1<<<dim3(8192), blk, 0, stream>>>(meas, w1, b1, h);

    gemm_bt<bf16_t, float><<<g6, blk, 0, stream>>>(h, w2, b2, ffnp, 3072, 3072, 3072, 768);

    ln_fuse<<<dim3(8192), blk, 0, stream>>>(y, ffnp, g2, be2, out, nullptr, nullptr);
}

// Round 5
// 359.503 us; speedup vs baseline: 6.3960x; 1.3055x over previous
//
#include <hip/hip_runtime.h>
#include <hip/hip_bf16.h>
#include <type_traits>

// TransformerBlockQuantum: B=4 S=2048 E=768 H=12 DK=64 FFN=3072 NQ=8
//   qkv = x@Wq/k/v^T + b         (merged bf16 MFMA GEMM -> qkv bf16 [8192,2304])
//   ctx = flash_attn(q,k,v,mask) (bf16 MFMA flash, no-max softmax)
//   attnp = ctx@wo^T + bo        (GEMM, fp32 out)
//   y = LN(x + attnp); meas = cos(y[:,:8]+theta)
//   h = relu(meas@w1^T + b1)     (bf16 [8192,3072])
//   ffnp = h@w2^T + b2           (GEMM, fp32 out)
//   out = LN(y + ffnp)

typedef __bf16 bf16_t;
typedef bf16_t bf16x4 __attribute__((ext_vector_type(4)));
typedef bf16_t bf16x8 __attribute__((ext_vector_type(8)));
typedef float floatx4 __attribute__((ext_vector_type(4)));

#define LOG2E 1.44269504088896f

// ---------------- GEMM: C[M,N] = A[M,K] @ W[N,K]^T + bias ----------------
template<typename TA, typename TC>
__global__ __launch_bounds__(256)
void gemm_bt(const TA* __restrict__ A, const float* __restrict__ W,
             const float* __restrict__ bias, TC* __restrict__ C,
             int K, int lda, int ldw, int ldc)
{
    __shared__ bf16_t As[128][48];
    __shared__ bf16_t Bs[128][48];
    const int tid  = threadIdx.x;
    const int wave = tid >> 6;
    const int lane = tid & 63;
    const int wm = (wave >> 1) * 64;
    const int wn = (wave & 1) * 64;
    const int bm = blockIdx.y * 128;
    const int bn = blockIdx.x * 128;

    const int srow = tid >> 3;
    const int scol = (tid & 7) * 4;
    const int fr = lane & 15;
    const int fk = (lane >> 4) * 8;

    floatx4 acc[4][4] = {};

    for (int k0 = 0; k0 < K; k0 += 32) {
        #pragma unroll
        for (int p = 0; p < 4; ++p) {
            const int r = srow + p * 32;
            bf16x4 va, vb;
            if constexpr (std::is_same<TA, float>::value) {
                const float4 f = *(const float4*)(A + (size_t)(bm + r) * lda + k0 + scol);
                va[0] = (bf16_t)f.x; va[1] = (bf16_t)f.y;
                va[2] = (bf16_t)f.z; va[3] = (bf16_t)f.w;
            } else {
                va = *(const bf16x4*)(A + (size_t)(bm + r) * lda + k0 + scol);
            }
            {
                const float4 f = *(const float4*)(W + (size_t)(bn + r) * ldw + k0 + scol);
                vb[0] = (bf16_t)f.x; vb[1] = (bf16_t)f.y;
                vb[2] = (bf16_t)f.z; vb[3] = (bf16_t)f.w;
            }
            *(bf16x4*)&As[r][scol] = va;
            *(bf16x4*)&Bs[r][scol] = vb;
        }
        __syncthreads();

        bf16x8 fa[4], fb[4];
        #pragma unroll
        for (int i = 0; i < 4; ++i) {
            fa[i] = *(const bf16x8*)&As[wm + i * 16 + fr][fk];
            fb[i] = *(const bf16x8*)&Bs[wn + i * 16 + fr][fk];
        }
        #pragma unroll
        for (int mi = 0; mi < 4; ++mi)
            #pragma unroll
            for (int ni = 0; ni < 4; ++ni)
                acc[mi][ni] = __builtin_amdgcn_mfma_f32_16x16x32_bf16(
                    fa[mi], fb[ni], acc[mi][ni], 0, 0, 0);
        __syncthreads();
    }

    const int fg = (lane >> 4) * 4;
    #pragma unroll
    for (int mi = 0; mi < 4; ++mi) {
        #pragma unroll
        for (int ni = 0; ni < 4; ++ni) {
            const int col = bn + wn + ni * 16 + fr;
            const float bv = bias[col];
            #pragma unroll
            for (int r = 0; r < 4; ++r) {
                const int row = bm + wm + mi * 16 + fg + r;
                C[(size_t)row * ldc + col] = (TC)(acc[mi][ni][r] + bv);
            }
        }
    }
}

// ---------------- merged QKV GEMM: one dispatch, N=2304 ----------------
__global__ __launch_bounds__(256)
void gemm_qkv(const float* __restrict__ x,
              const float* __restrict__ wq, const float* __restrict__ wk,
              const float* __restrict__ wv,
              const float* __restrict__ bq, const float* __restrict__ bk,
              const float* __restrict__ bv,
              bf16_t* __restrict__ qkv)
{
    __shared__ bf16_t As[128][48];
    __shared__ bf16_t Bs[128][48];
    const int sect = blockIdx.x / 6;            // 0=q 1=k 2=v
    const int bn   = (blockIdx.x % 6) * 128;
    const float* W    = sect == 0 ? wq : (sect == 1 ? wk : wv);
    const float* bias = sect == 0 ? bq : (sect == 1 ? bk : bv);

    const int tid  = threadIdx.x;
    const int wave = tid >> 6;
    const int lane = tid & 63;
    const int wm = (wave >> 1) * 64;
    const int wn = (wave & 1) * 64;
    const int bm = blockIdx.y * 128;

    const int srow = tid >> 3;
    const int scol = (tid & 7) * 4;
    const int fr = lane & 15;
    const int fk = (lane >> 4) * 8;

    floatx4 acc[4][4] = {};

    for (int k0 = 0; k0 < 768; k0 += 32) {
        #pragma unroll
        for (int p = 0; p < 4; ++p) {
            const int r = srow + p * 32;
            const float4 fa4 = *(const float4*)(x + (size_t)(bm + r) * 768 + k0 + scol);
            const float4 fb4 = *(const float4*)(W + (size_t)(bn + r) * 768 + k0 + scol);
            bf16x4 va, vb;
            va[0] = (bf16_t)fa4.x; va[1] = (bf16_t)fa4.y;
            va[2] = (bf16_t)fa4.z; va[3] = (bf16_t)fa4.w;
            vb[0] = (bf16_t)fb4.x; vb[1] = (bf16_t)fb4.y;
            vb[2] = (bf16_t)fb4.z; vb[3] = (bf16_t)fb4.w;
            *(bf16x4*)&As[r][scol] = va;
            *(bf16x4*)&Bs[r][scol] = vb;
        }
        __syncthreads();

        bf16x8 fa[4], fb[4];
        #pragma unroll
        for (int i = 0; i < 4; ++i) {
            fa[i] = *(const bf16x8*)&As[wm + i * 16 + fr][fk];
            fb[i] = *(const bf16x8*)&Bs[wn + i * 16 + fr][fk];
        }
        #pragma unroll
        for (int mi = 0; mi < 4; ++mi)
            #pragma unroll
            for (int ni = 0; ni < 4; ++ni)
                acc[mi][ni] = __builtin_amdgcn_mfma_f32_16x16x32_bf16(
                    fa[mi], fb[ni], acc[mi][ni], 0, 0, 0);
        __syncthreads();
    }

    const int fg = (lane >> 4) * 4;
    #pragma unroll
    for (int mi = 0; mi < 4; ++mi) {
        #pragma unroll
        for (int ni = 0; ni < 4; ++ni) {
            const int col = bn + wn + ni * 16 + fr;
            const float bv = bias[col];
            const int gcol = sect * 768 + col;
            #pragma unroll
            for (int r = 0; r < 4; ++r) {
                const int row = bm + wm + mi * 16 + fg + r;
                qkv[(size_t)row * 2304 + gcol] = (bf16_t)(acc[mi][ni][r] + bv);
            }
        }
    }
}

// ---------------- MFMA flash attention v2 ----------------
// Transposed QK^T (mfma(K,Q) -> S^T), no-max softmax p=exp2(s*log2e+mb),
// P packed bf16x4 -> one ds_write_b64 per (qt,ct), l via ones-column MFMA.
__global__ __launch_bounds__(256)
void attn_mfma(const bf16_t* __restrict__ qkv, const int* __restrict__ mask,
               bf16_t* __restrict__ ctx)
{
    __shared__ bf16_t Ks[64][72];     // K[key][d], 144B rows
    __shared__ bf16_t Vt[80][72];     // V^T[d][key]; row64=ones, 65..79=0
    __shared__ float  mb_s[64];
    __shared__ bf16_t Pl[4][32][72];  // per-wave P[q][key], 144B rows

    const int bh = blockIdx.y;
    const int b = bh / 12, h = bh % 12;
    const int tid  = threadIdx.x;
    const int wave = tid >> 6;
    const int lane = tid & 63;
    const int g    = lane >> 4;
    const int fr   = lane & 15;
    const int qbase = blockIdx.x * 128 + wave * 32;

    // init ones/zero rows of Vt (rows 64..79)
    for (int idx = tid; idx < 16 * 72; idx += 256) {
        const int rr = idx / 72, cc = idx % 72;
        Vt[64 + rr][cc] = (bf16_t)(rr == 0 ? 1.f : 0.f);
    }

    // Q fragments, scaled by 1/sqrt(64)=0.125 (exact in bf16)
    bf16x8 qf[2][2];
    #pragma unroll
    for (int qt = 0; qt < 2; ++qt)
        #pragma unroll
        for (int s = 0; s < 2; ++s) {
            const size_t tok = (size_t)(b * 2048 + qbase + qt * 16 + fr);
            qf[qt][s] = *(const bf16x8*)(qkv + tok * 2304 + h * 64 + s * 32 + g * 8);
            #pragma unroll
            for (int j = 0; j < 8; ++j)
                qf[qt][s][j] = (bf16_t)((float)qf[qt][s][j] * 0.125f);
        }

    floatx4 o[2][4] = {};
    floatx4 oe[2] = {};

    const int skey = tid & 63;
    const int sgrp = tid >> 6;

    for (int kt = 0; kt < 32; ++kt) {
        __syncthreads();
        {   // stage K row-major, V transposed
            const size_t ktok = (size_t)(b * 2048 + kt * 64 + skey) * 2304 + h * 64;
            const bf16x8 k0 = *(const bf16x8*)(qkv + ktok + 768 + sgrp * 16);
            const bf16x8 k1 = *(const bf16x8*)(qkv + ktok + 768 + sgrp * 16 + 8);
            *(bf16x8*)&Ks[skey][sgrp * 16]     = k0;
            *(bf16x8*)&Ks[skey][sgrp * 16 + 8] = k1;
            const bf16x8 v0 = *(const bf16x8*)(qkv + ktok + 1536 + sgrp * 16);
            const bf16x8 v1 = *(const bf16x8*)(qkv + ktok + 1536 + sgrp * 16 + 8);
            #pragma unroll
            for (int j = 0; j < 8; ++j) {
                Vt[sgrp * 16 + j][skey]     = v0[j];
                Vt[sgrp * 16 + 8 + j][skey] = v1[j];
            }
            if (tid < 64)
                mb_s[tid] = (mask[b * 2048 + kt * 64 + tid] == 0) ? -1e9f : 0.f;
        }
        __syncthreads();

        // ---- QK^T transposed: saccT[key][q] = mfma(K, Q) ----
        floatx4 st_[2][4] = {};
        #pragma unroll
        for (int s = 0; s < 2; ++s) {
            bf16x8 kf[4];
            #pragma unroll
            for (int ct = 0; ct < 4; ++ct)
                kf[ct] = *(const bf16x8*)&Ks[ct * 16 + fr][s * 32 + g * 8];
            #pragma unroll
            for (int qt = 0; qt < 2; ++qt)
                #pragma unroll
                for (int ct = 0; ct < 4; ++ct)
                    st_[qt][ct] = __builtin_amdgcn_mfma_f32_16x16x32_bf16(
                        kf[ct], qf[qt][s], st_[qt][ct], 0, 0, 0);
        }

        // ---- softmax (no max): p = exp2(s*log2e + mb); pack 4 keys -> b64 ----
        #pragma unroll
        for (int qt = 0; qt < 2; ++qt) {
            #pragma unroll
            for (int ct = 0; ct < 4; ++ct) {
                const float4 mb4 = *(const float4*)&mb_s[ct * 16 + g * 4];
                const float mbr[4] = { mb4.x, mb4.y, mb4.z, mb4.w };
                bf16x4 pw;
                #pragma unroll
                for (int r = 0; r < 4; ++r)
                    pw[r] = (bf16_t)__builtin_amdgcn_exp2f(
                        fmaf(st_[qt][ct][r], LOG2E, mbr[r]));
                *(bf16x4*)&Pl[wave][qt * 16 + fr][ct * 16 + g * 4] = pw;
            }
        }

        // ---- PV + ones-column l (wave-local Pl, no barrier) ----
        #pragma unroll
        for (int st2 = 0; st2 < 2; ++st2) {
            bf16x8 pf[2];
            #pragma unroll
            for (int qt = 0; qt < 2; ++qt)
                pf[qt] = *(const bf16x8*)&Pl[wave][qt * 16 + fr][st2 * 32 + g * 8];
            #pragma unroll
            for (int dt = 0; dt < 4; ++dt) {
                const bf16x8 vf = *(const bf16x8*)&Vt[dt * 16 + fr][st2 * 32 + g * 8];
                #pragma unroll
                for (int qt = 0; qt < 2; ++qt)
                    o[qt][dt] = __builtin_amdgcn_mfma_f32_16x16x32_bf16(
                        pf[qt], vf, o[qt][dt], 0, 0, 0);
            }
            const bf16x8 vo = *(const bf16x8*)&Vt[64 + fr][st2 * 32 + g * 8];
            #pragma unroll
            for (int qt = 0; qt < 2; ++qt)
                oe[qt] = __builtin_amdgcn_mfma_f32_16x16x32_bf16(
                    pf[qt], vo, oe[qt], 0, 0, 0);
        }
    }

    // ---- epilogue: broadcast l from fr=0 lanes, normalize, store ----
    #pragma unroll
    for (int qt = 0; qt < 2; ++qt) {
        float inv[4];
        #pragma unroll
        for (int r = 0; r < 4; ++r) {
            const float lv = __shfl(oe[qt][r], (lane & 48), 64);
            inv[r] = 1.f / lv;
        }
        #pragma unroll
        for (int dt = 0; dt < 4; ++dt)
            #pragma unroll
            for (int r = 0; r < 4; ++r) {
                const size_t row = (size_t)(b * 2048 + qbase + qt * 16 + g * 4 + r);
                ctx[row * 768 + h * 64 + dt * 16 + fr] = (bf16_t)(o[qt][dt][r] * inv[r]);
            }
    }
}

// ---------------- fused residual + LayerNorm (+ optional meas) ----------------
__global__ __launch_bounds__(256)
void ln_fuse(const float* __restrict__ xin, const float* __restrict__ proj,
             const float* __restrict__ g, const float* __restrict__ be,
             float* __restrict__ out,
             const float* __restrict__ theta, float* __restrict__ meas)
{
    const int row = blockIdx.x;
    const int tid = threadIdx.x;
    const size_t base = (size_t)row * 768;
    const float v0 = xin[base + tid]       + proj[base + tid];
    const float v1 = xin[base + tid + 256] + proj[base + tid + 256];
    const float v2 = xin[base + tid + 512] + proj[base + tid + 512];
    float s1 = v0 + v1 + v2;
    float s2 = v0*v0 + v1*v1 + v2*v2;
    #pragma unroll
    for (int mk = 32; mk >= 1; mk >>= 1) {
        s1 += __shfl_xor(s1, mk, 64);
        s2 += __shfl_xor(s2, mk, 64);
    }
    __shared__ float w1s[4], w2s[4];
    const int wave = tid >> 6;
    if ((tid & 63) == 0) { w1s[wave] = s1; w2s[wave] = s2; }
    __syncthreads();
    const float tot1 = w1s[0] + w1s[1] + w1s[2] + w1s[3];
    const float tot2 = w2s[0] + w2s[1] + w2s[2] + w2s[3];
    const float mu   = tot1 * (1.f / 768.f);
    const float var  = tot2 * (1.f / 768.f) - mu * mu;
    const float rinv = rsqrtf(var + 1e-5f);
    const float y0 = (v0 - mu) * rinv * g[tid] + be[tid];
    out[base + tid]       = y0;
    out[base + tid + 256] = (v1 - mu) * rinv * g[tid + 256] + be[tid + 256];
    out[base + tid + 512] = (v2 - mu) * rinv * g[tid + 512] + be[tid + 512];
    if (meas != nullptr && tid < 8)
        meas[row * 8 + tid] = cosf(y0 + theta[tid]);
}

// ---------------- quantum FFN stage 1 ----------------
__global__ __launch_bounds__(256)
void ffn1(const float* __restrict__ meas, const float* __restrict__ w1,
          const float* __restrict__ b1, bf16_t* __restrict__ h)
{
    const int row = blockIdx.x;
    __shared__ float ms[8];
    if (threadIdx.x < 8) ms[threadIdx.x] = meas[row * 8 + threadIdx.x];
    __syncthreads();
    #pragma unroll
    for (int i = 0; i < 12; ++i) {
        const int f = threadIdx.x + i * 256;
        const float4 wa = *(const float4*)(w1 + f * 8);
        const float4 wb = *(const float4*)(w1 + f * 8 + 4);
        float v = b1[f];
        v += ms[0]*wa.x + ms[1]*wa.y + ms[2]*wa.z + ms[3]*wa.w;
        v += ms[4]*wb.x + ms[5]*wb.y + ms[6]*wb.z + ms[7]*wb.w;
        h[(size_t)row * 3072 + f] = (bf16_t)fmaxf(v, 0.f);
    }
}

extern "C" void kernel_launch(void* const* d_in, const int* in_sizes, int n_in,
                              void* d_out, int out_size, void* d_ws, size_t ws_size,
                              hipStream_t stream)
{
    const float* x     = (const float*)d_in[0];
    const int*   mask  = (const int*)d_in[1];
    const float* wq    = (const float*)d_in[2];
    const float* bq    = (const float*)d_in[3];
    const float* wk    = (const float*)d_in[4];
    const float* bk    = (const float*)d_in[5];
    const float* wv    = (const float*)d_in[6];
    const float* bv    = (const float*)d_in[7];
    const float* wo    = (const float*)d_in[8];
    const float* bo    = (const float*)d_in[9];
    const float* g1    = (const float*)d_in[10];
    const float* be1   = (const float*)d_in[11];
    const float* g2    = (const float*)d_in[12];
    const float* be2   = (const float*)d_in[13];
    const float* theta = (const float*)d_in[14];
    const float* w1    = (const float*)d_in[15];
    const float* b1    = (const float*)d_in[16];
    const float* w2    = (const float*)d_in[17];
    const float* b2    = (const float*)d_in[18];
    float* out = (float*)d_out;

    char* ws = (char*)d_ws;
    bf16_t* qkv   = (bf16_t*)(ws + 0);
    bf16_t* ctx   = (bf16_t*)(ws + 37748736);
    float*  attnp = (float*)(ws + 50331648);
    float*  y     = (float*)(ws + 75497472);
    float*  meas  = (float*)(ws + 100663296);
    bf16_t* h     = (bf16_t*)(ws + 100925440);
    float*  ffnp  = (float*)(ws + 0);   // aliases qkv (dead after attention)

    const dim3 blk(256);

    gemm_qkv<<<dim3(18, 64), blk, 0, stream>>>(x, wq, wk, wv, bq, bk, bv, qkv);

    attn_mfma<<<dim3(16, 48), blk, 0, stream>>>(qkv, mask, ctx);

    gemm_bt<bf16_t, float><<<dim3(6, 64), blk, 0, stream>>>(ctx, wo, bo, attnp, 768, 768, 768, 768);

    ln_fuse<<<dim3(8192), blk, 0, stream>>>(x, attnp, g1, be1, y, theta, meas);

    ffn1<<<dim3(8192), blk, 0, stream>>>(meas, w1, b1, h);

    gemm_bt<bf16_t, float><<<dim3(6, 64), blk, 0, stream>>>(h, w2, b2, ffnp, 3072, 3072, 3072, 768);

    ln_fuse<<<dim3(8192), blk, 0, stream>>>(y, ffnp, g2, be2, out, nullptr, nullptr);
}

// Round 6
// 319.906 us; speedup vs baseline: 7.1877x; 1.1238x over previous
//
#include <hip/hip_runtime.h>
#include <hip/hip_bf16.h>

// TransformerBlockQuantum: B=4 S=2048 E=768 H=12 DK=64 FFN=3072 NQ=8
// prep: cast x->xb bf16, pack wq/wk/wv -> wqkv bf16 [2304,768] (+bqkv), wo->wob, w2->w2b
//   qkv  = xb@wqkv^T + bqkv      (gemm_bb -> bf16 [8192,2304])
//   ctx  = flash_attn(qkv,mask)  (bf16 MFMA flash, no-max softmax)
//   attnp= ctx@wob^T + bo        (gemm_bb split-K=2, fp32 partials)
//   y    = LN(x + attnp_a+attnp_b); meas = cos(y[:,:8]+theta)
//   h    = relu(meas@w1^T + b1)  (bf16 [8192,3072])
//   ffnp = h@w2b^T + b2          (gemm_bb split-K=2, fp32 partials)
//   out  = LN(y + ffnp_a+ffnp_b)

typedef __bf16 bf16_t;
typedef bf16_t bf16x4 __attribute__((ext_vector_type(4)));
typedef bf16_t bf16x8 __attribute__((ext_vector_type(8)));
typedef float floatx4 __attribute__((ext_vector_type(4)));

#define LOG2E 1.44269504088896f

// ---- async global->LDS, 16B per lane (m97 pattern) ----
__device__ __forceinline__ void gload16(const bf16_t* g, bf16_t* l) {
    __builtin_amdgcn_global_load_lds(
        (const __attribute__((address_space(1))) unsigned int*)g,
        (__attribute__((address_space(3))) unsigned int*)l,
        16, 0, 0);
}

// ---------------- prep: fp32 -> bf16 conversions / packing ----------------
__global__ __launch_bounds__(256)
void prep(const float* __restrict__ x,
          const float* __restrict__ wq, const float* __restrict__ wk,
          const float* __restrict__ wv, const float* __restrict__ wo,
          const float* __restrict__ w2,
          const float* __restrict__ bq, const float* __restrict__ bk,
          const float* __restrict__ bv,
          bf16_t* __restrict__ xb, bf16_t* __restrict__ wqkv,
          bf16_t* __restrict__ wob, bf16_t* __restrict__ w2b,
          float* __restrict__ bqkv)
{
    const int seg = blockIdx.y;
    const int idx = blockIdx.x * 256 + threadIdx.x;   // float4 index
    if (seg == 0) {                      // xb: 8192*768
        if (idx >= 1572864) return;
        const float4 f = ((const float4*)x)[idx];
        bf16x4 o = {(bf16_t)f.x, (bf16_t)f.y, (bf16_t)f.z, (bf16_t)f.w};
        ((bf16x4*)xb)[idx] = o;
    } else if (seg == 1) {               // wqkv: 3*768*768 packed q|k|v
        if (idx >= 442368) return;
        const int e = idx * 4;
        const float4 f = (e < 589824) ? ((const float4*)wq)[idx]
                       : (e < 1179648) ? ((const float4*)wk)[idx - 147456]
                                       : ((const float4*)wv)[idx - 294912];
        bf16x4 o = {(bf16_t)f.x, (bf16_t)f.y, (bf16_t)f.z, (bf16_t)f.w};
        ((bf16x4*)wqkv)[idx] = o;
    } else if (seg == 2) {               // wob: 768*768
        if (idx >= 147456) return;
        const float4 f = ((const float4*)wo)[idx];
        bf16x4 o = {(bf16_t)f.x, (bf16_t)f.y, (bf16_t)f.z, (bf16_t)f.w};
        ((bf16x4*)wob)[idx] = o;
    } else if (seg == 3) {               // w2b: 768*3072
        if (idx >= 589824) return;
        const float4 f = ((const float4*)w2)[idx];
        bf16x4 o = {(bf16_t)f.x, (bf16_t)f.y, (bf16_t)f.z, (bf16_t)f.w};
        ((bf16x4*)w2b)[idx] = o;
    } else {                             // bqkv: 2304 fp32 concat
        if (idx >= 576) return;
        const int e = idx * 4;
        const float4 f = (e < 768) ? ((const float4*)bq)[idx]
                       : (e < 1536) ? ((const float4*)bk)[idx - 192]
                                    : ((const float4*)bv)[idx - 384];
        ((float4*)bqkv)[idx] = f;
    }
}

// ---------------- GEMM (all-bf16 operands): C = A[M,K]@W[N,K]^T + bias ----------------
// 128x128 tile, BK=32, 4 waves 2x2, global_load_lds staging, linear [128][32] LDS.
// gridDim.z = split-K count; partial z writes C + z*splitStride, bias only on z=0.
template<typename TC>
__global__ __launch_bounds__(256)
void gemm_bb(const bf16_t* __restrict__ A, const bf16_t* __restrict__ W,
             const float* __restrict__ bias, TC* __restrict__ C,
             int kPer, int lda, int ldw, int ldc, int splitStride)
{
    __shared__ __align__(16) bf16_t As[4096];   // [128][32]
    __shared__ __align__(16) bf16_t Bs[4096];
    const int tid  = threadIdx.x;
    const int wave = tid >> 6;
    const int lane = tid & 63;
    const int wm = (wave >> 1) * 64;
    const int wn = (wave & 1) * 64;
    const int bm = blockIdx.y * 128;
    const int bn = blockIdx.x * 128;
    const int fr = lane & 15;
    const int fk = (lane >> 4) * 8;

    const int kBeg = blockIdx.z * kPer;
    const int kEnd = kBeg + kPer;
    C += (size_t)blockIdx.z * splitStride;

    const int srow = tid >> 2;          // 0..63
    const int scol = (tid & 3) * 8;     // 0,8,16,24
    bf16_t* lA = &As[tid * 8];
    bf16_t* lB = &Bs[tid * 8];

    floatx4 acc[4][4] = {};

    for (int k0 = kBeg; k0 < kEnd; k0 += 32) {
        const bf16_t* ga = A + (size_t)(bm + srow) * lda + k0 + scol;
        const bf16_t* gb = W + (size_t)(bn + srow) * ldw + k0 + scol;
        gload16(ga,                     lA);
        gload16(ga + (size_t)64 * lda,  lA + 2048);
        gload16(gb,                     lB);
        gload16(gb + (size_t)64 * ldw,  lB + 2048);
        __syncthreads();   // drains vmcnt -> LDS tiles ready

        bf16x8 fa[4], fb[4];
        #pragma unroll
        for (int i = 0; i < 4; ++i) {
            fa[i] = *(const bf16x8*)&As[(wm + i * 16 + fr) * 32 + fk];
            fb[i] = *(const bf16x8*)&Bs[(wn + i * 16 + fr) * 32 + fk];
        }
        #pragma unroll
        for (int mi = 0; mi < 4; ++mi)
            #pragma unroll
            for (int ni = 0; ni < 4; ++ni)
                acc[mi][ni] = __builtin_amdgcn_mfma_f32_16x16x32_bf16(
                    fa[mi], fb[ni], acc[mi][ni], 0, 0, 0);
        __syncthreads();   // all reads done before next stage
    }

    const int fg = (lane >> 4) * 4;
    const bool addb = (blockIdx.z == 0);
    #pragma unroll
    for (int mi = 0; mi < 4; ++mi) {
        #pragma unroll
        for (int ni = 0; ni < 4; ++ni) {
            const int col = bn + wn + ni * 16 + fr;
            const float bv = addb ? bias[col] : 0.f;
            #pragma unroll
            for (int r = 0; r < 4; ++r) {
                const int row = bm + wm + mi * 16 + fg + r;
                C[(size_t)row * ldc + col] = (TC)(acc[mi][ni][r] + bv);
            }
        }
    }
}

// ---------------- MFMA flash attention v2 (unchanged, verified) ----------------
__global__ __launch_bounds__(256)
void attn_mfma(const bf16_t* __restrict__ qkv, const int* __restrict__ mask,
               bf16_t* __restrict__ ctx)
{
    __shared__ bf16_t Ks[64][72];     // K[key][d], 144B rows
    __shared__ bf16_t Vt[80][72];     // V^T[d][key]; row64=ones, 65..79=0
    __shared__ float  mb_s[64];
    __shared__ bf16_t Pl[4][32][72];  // per-wave P[q][key], 144B rows

    const int bh = blockIdx.y;
    const int b = bh / 12, h = bh % 12;
    const int tid  = threadIdx.x;
    const int wave = tid >> 6;
    const int lane = tid & 63;
    const int g    = lane >> 4;
    const int fr   = lane & 15;
    const int qbase = blockIdx.x * 128 + wave * 32;

    for (int idx = tid; idx < 16 * 72; idx += 256) {
        const int rr = idx / 72, cc = idx % 72;
        Vt[64 + rr][cc] = (bf16_t)(rr == 0 ? 1.f : 0.f);
    }

    bf16x8 qf[2][2];
    #pragma unroll
    for (int qt = 0; qt < 2; ++qt)
        #pragma unroll
        for (int s = 0; s < 2; ++s) {
            const size_t tok = (size_t)(b * 2048 + qbase + qt * 16 + fr);
            qf[qt][s] = *(const bf16x8*)(qkv + tok * 2304 + h * 64 + s * 32 + g * 8);
            #pragma unroll
            for (int j = 0; j < 8; ++j)
                qf[qt][s][j] = (bf16_t)((float)qf[qt][s][j] * 0.125f);
        }

    floatx4 o[2][4] = {};
    floatx4 oe[2] = {};

    const int skey = tid & 63;
    const int sgrp = tid >> 6;

    for (int kt = 0; kt < 32; ++kt) {
        __syncthreads();
        {
            const size_t ktok = (size_t)(b * 2048 + kt * 64 + skey) * 2304 + h * 64;
            const bf16x8 k0 = *(const bf16x8*)(qkv + ktok + 768 + sgrp * 16);
            const bf16x8 k1 = *(const bf16x8*)(qkv + ktok + 768 + sgrp * 16 + 8);
            *(bf16x8*)&Ks[skey][sgrp * 16]     = k0;
            *(bf16x8*)&Ks[skey][sgrp * 16 + 8] = k1;
            const bf16x8 v0 = *(const bf16x8*)(qkv + ktok + 1536 + sgrp * 16);
            const bf16x8 v1 = *(const bf16x8*)(qkv + ktok + 1536 + sgrp * 16 + 8);
            #pragma unroll
            for (int j = 0; j < 8; ++j) {
                Vt[sgrp * 16 + j][skey]     = v0[j];
                Vt[sgrp * 16 + 8 + j][skey] = v1[j];
            }
            if (tid < 64)
                mb_s[tid] = (mask[b * 2048 + kt * 64 + tid] == 0) ? -1e9f : 0.f;
        }
        __syncthreads();

        floatx4 st_[2][4] = {};
        #pragma unroll
        for (int s = 0; s < 2; ++s) {
            bf16x8 kf[4];
            #pragma unroll
            for (int ct = 0; ct < 4; ++ct)
                kf[ct] = *(const bf16x8*)&Ks[ct * 16 + fr][s * 32 + g * 8];
            #pragma unroll
            for (int qt = 0; qt < 2; ++qt)
                #pragma unroll
                for (int ct = 0; ct < 4; ++ct)
                    st_[qt][ct] = __builtin_amdgcn_mfma_f32_16x16x32_bf16(
                        kf[ct], qf[qt][s], st_[qt][ct], 0, 0, 0);
        }

        #pragma unroll
        for (int qt = 0; qt < 2; ++qt) {
            #pragma unroll
            for (int ct = 0; ct < 4; ++ct) {
                const float4 mb4 = *(const float4*)&mb_s[ct * 16 + g * 4];
                const float mbr[4] = { mb4.x, mb4.y, mb4.z, mb4.w };
                bf16x4 pw;
                #pragma unroll
                for (int r = 0; r < 4; ++r)
                    pw[r] = (bf16_t)__builtin_amdgcn_exp2f(
                        fmaf(st_[qt][ct][r], LOG2E, mbr[r]));
                *(bf16x4*)&Pl[wave][qt * 16 + fr][ct * 16 + g * 4] = pw;
            }
        }

        #pragma unroll
        for (int st2 = 0; st2 < 2; ++st2) {
            bf16x8 pf[2];
            #pragma unroll
            for (int qt = 0; qt < 2; ++qt)
                pf[qt] = *(const bf16x8*)&Pl[wave][qt * 16 + fr][st2 * 32 + g * 8];
            #pragma unroll
            for (int dt = 0; dt < 4; ++dt) {
                const bf16x8 vf = *(const bf16x8*)&Vt[dt * 16 + fr][st2 * 32 + g * 8];
                #pragma unroll
                for (int qt = 0; qt < 2; ++qt)
                    o[qt][dt] = __builtin_amdgcn_mfma_f32_16x16x32_bf16(
                        pf[qt], vf, o[qt][dt], 0, 0, 0);
            }
            const bf16x8 vo = *(const bf16x8*)&Vt[64 + fr][st2 * 32 + g * 8];
            #pragma unroll
            for (int qt = 0; qt < 2; ++qt)
                oe[qt] = __builtin_amdgcn_mfma_f32_16x16x32_bf16(
                    pf[qt], vo, oe[qt], 0, 0, 0);
        }
    }

    #pragma unroll
    for (int qt = 0; qt < 2; ++qt) {
        float inv[4];
        #pragma unroll
        for (int r = 0; r < 4; ++r) {
            const float lv = __shfl(oe[qt][r], (lane & 48), 64);
            inv[r] = 1.f / lv;
        }
        #pragma unroll
        for (int dt = 0; dt < 4; ++dt)
            #pragma unroll
            for (int r = 0; r < 4; ++r) {
                const size_t row = (size_t)(b * 2048 + qbase + qt * 16 + g * 4 + r);
                ctx[row * 768 + h * 64 + dt * 16 + fr] = (bf16_t)(o[qt][dt][r] * inv[r]);
            }
    }
}

// ---------------- fused residual + LayerNorm (2 split-K partials) ----------------
__global__ __launch_bounds__(256)
void ln_fuse(const float* __restrict__ xin, const float* __restrict__ proj,
             const float* __restrict__ proj2,
             const float* __restrict__ g, const float* __restrict__ be,
             float* __restrict__ out,
             const float* __restrict__ theta, float* __restrict__ meas)
{
    const int row = blockIdx.x;
    const int tid = threadIdx.x;
    const size_t base = (size_t)row * 768;
    float v0 = xin[base + tid]       + proj[base + tid];
    float v1 = xin[base + tid + 256] + proj[base + tid + 256];
    float v2 = xin[base + tid + 512] + proj[base + tid + 512];
    if (proj2 != nullptr) {
        v0 += proj2[base + tid];
        v1 += proj2[base + tid + 256];
        v2 += proj2[base + tid + 512];
    }
    float s1 = v0 + v1 + v2;
    float s2 = v0*v0 + v1*v1 + v2*v2;
    #pragma unroll
    for (int mk = 32; mk >= 1; mk >>= 1) {
        s1 += __shfl_xor(s1, mk, 64);
        s2 += __shfl_xor(s2, mk, 64);
    }
    __shared__ float w1s[4], w2s[4];
    const int wave = tid >> 6;
    if ((tid & 63) == 0) { w1s[wave] = s1; w2s[wave] = s2; }
    __syncthreads();
    const float tot1 = w1s[0] + w1s[1] + w1s[2] + w1s[3];
    const float tot2 = w2s[0] + w2s[1] + w2s[2] + w2s[3];
    const float mu   = tot1 * (1.f / 768.f);
    const float var  = tot2 * (1.f / 768.f) - mu * mu;
    const float rinv = rsqrtf(var + 1e-5f);
    const float y0 = (v0 - mu) * rinv * g[tid] + be[tid];
    out[base + tid]       = y0;
    out[base + tid + 256] = (v1 - mu) * rinv * g[tid + 256] + be[tid + 256];
    out[base + tid + 512] = (v2 - mu) * rinv * g[tid + 512] + be[tid + 512];
    if (meas != nullptr && tid < 8)
        meas[row * 8 + tid] = cosf(y0 + theta[tid]);
}

// ---------------- quantum FFN stage 1 ----------------
__global__ __launch_bounds__(256)
void ffn1(const float* __restrict__ meas, const float* __restrict__ w1,
          const float* __restrict__ b1, bf16_t* __restrict__ h)
{
    const int row = blockIdx.x;
    __shared__ float ms[8];
    if (threadIdx.x < 8) ms[threadIdx.x] = meas[row * 8 + threadIdx.x];
    __syncthreads();
    #pragma unroll
    for (int i = 0; i < 12; ++i) {
        const int f = threadIdx.x + i * 256;
        const float4 wa = *(const float4*)(w1 + f * 8);
        const float4 wb = *(const float4*)(w1 + f * 8 + 4);
        float v = b1[f];
        v += ms[0]*wa.x + ms[1]*wa.y + ms[2]*wa.z + ms[3]*wa.w;
        v += ms[4]*wb.x + ms[5]*wb.y + ms[6]*wb.z + ms[7]*wb.w;
        h[(size_t)row * 3072 + f] = (bf16_t)fmaxf(v, 0.f);
    }
}

extern "C" void kernel_launch(void* const* d_in, const int* in_sizes, int n_in,
                              void* d_out, int out_size, void* d_ws, size_t ws_size,
                              hipStream_t stream)
{
    const float* x     = (const float*)d_in[0];
    const int*   mask  = (const int*)d_in[1];
    const float* wq    = (const float*)d_in[2];
    const float* bq    = (const float*)d_in[3];
    const float* wk    = (const float*)d_in[4];
    const float* bk    = (const float*)d_in[5];
    const float* wv    = (const float*)d_in[6];
    const float* bv    = (const float*)d_in[7];
    const float* wo    = (const float*)d_in[8];
    const float* bo    = (const float*)d_in[9];
    const float* g1    = (const float*)d_in[10];
    const float* be1   = (const float*)d_in[11];
    const float* g2    = (const float*)d_in[12];
    const float* be2   = (const float*)d_in[13];
    const float* theta = (const float*)d_in[14];
    const float* w1    = (const float*)d_in[15];
    const float* b1    = (const float*)d_in[16];
    const float* w2    = (const float*)d_in[17];
    const float* b2    = (const float*)d_in[18];
    float* out = (float*)d_out;

    char* ws = (char*)d_ws;
    // layout (bytes):
    bf16_t* qkv    = (bf16_t*)(ws + 0);           // 37748736; reused by ffnp after attn
    bf16_t* ctx    = (bf16_t*)(ws + 37748736);    // 12582912
    float*  attnp  = (float*)(ws + 50331648);     // 2 x 25165824; reused by h after ln1
    float*  y      = (float*)(ws + 100663296);    // 25165824
    float*  meas   = (float*)(ws + 125829120);    // 262144
    bf16_t* xb     = (bf16_t*)(ws + 126091264);   // 12582912
    bf16_t* wqkv   = (bf16_t*)(ws + 138674176);   // 3538944
    bf16_t* wob    = (bf16_t*)(ws + 142213120);   // 1179648
    bf16_t* w2b    = (bf16_t*)(ws + 143392768);   // 4718592
    float*  bqkv   = (float*)(ws + 148111360);    // 9216
    float*  ffnp   = (float*)(ws + 0);            // 2 x 25165824 (aliases qkv+ctx)
    bf16_t* h      = (bf16_t*)(ws + 50331648);    // 50331648 (aliases attnp)

    const dim3 blk(256);

    prep<<<dim3(6144, 5), blk, 0, stream>>>(x, wq, wk, wv, wo, w2, bq, bk, bv,
                                            xb, wqkv, wob, w2b, bqkv);

    // qkv = xb @ wqkv^T + bqkv   [8192,2304] bf16
    gemm_bb<bf16_t><<<dim3(18, 64, 1), blk, 0, stream>>>(
        xb, wqkv, bqkv, qkv, 768, 768, 768, 2304, 0);

    attn_mfma<<<dim3(16, 48), blk, 0, stream>>>(qkv, mask, ctx);

    // attnp = ctx @ wob^T + bo   split-K=2 fp32 partials
    gemm_bb<float><<<dim3(6, 64, 2), blk, 0, stream>>>(
        ctx, wob, bo, attnp, 384, 768, 768, 768, 6291456);

    ln_fuse<<<dim3(8192), blk, 0, stream>>>(x, attnp, attnp + 6291456,
                                            g1, be1, y, theta, meas);

    ffn1<<<dim3(8192), blk, 0, stream>>>(meas, w1, b1, h);

    // ffnp = h @ w2b^T + b2      split-K=2 fp32 partials
    gemm_bb<float><<<dim3(6, 64, 2), blk, 0, stream>>>(
        h, w2b, b2, ffnp, 1536, 3072, 3072, 768, 6291456);

    ln_fuse<<<dim3(8192), blk, 0, stream>>>(y, ffnp, ffnp + 6291456,
                                            g2, be2, out, nullptr, nullptr);
}

// Round 7
// 292.978 us; speedup vs baseline: 7.8483x; 1.0919x over previous
//
#include <hip/hip_runtime.h>
#include <hip/hip_bf16.h>

// TransformerBlockQuantum: B=4 S=2048 E=768 H=12 DK=64 FFN=3072 NQ=8
// prep: x->xb bf16, pack wq*0.125|wk|wv -> wqkv bf16 (+bqkv, bq*0.125), wo->wob, w2->w2b
//   qkv  = xb@wqkv^T + bqkv      (gemm_bb dbuf -> bf16 [8192,2304], q pre-scaled)
//   ctx  = flash_attn(qkv,mask)  (bf16 MFMA flash, no-max softmax, reg-prefetch, XCD swizzle)
//   attnp= ctx@wob^T + bo        (gemm_bb split-K=2, fp32 partials)
//   y    = LN(x + attnp_a+attnp_b); meas = cos(y[:,:8]+theta)
//   h    = relu(meas@w1^T + b1)  (bf16 [8192,3072])
//   ffnp = h@w2b^T + b2          (gemm_bb split-K=2, fp32 partials)
//   out  = LN(y + ffnp_a+ffnp_b)

typedef __bf16 bf16_t;
typedef bf16_t bf16x4 __attribute__((ext_vector_type(4)));
typedef bf16_t bf16x8 __attribute__((ext_vector_type(8)));
typedef float floatx4 __attribute__((ext_vector_type(4)));

#define LOG2E 1.44269504088896f

// ---- async global->LDS, 16B per lane ----
__device__ __forceinline__ void gload16(const bf16_t* g, bf16_t* l) {
    __builtin_amdgcn_global_load_lds(
        (const __attribute__((address_space(1))) unsigned int*)g,
        (__attribute__((address_space(3))) unsigned int*)l,
        16, 0, 0);
}

// ---------------- prep: fp32 -> bf16 conversions / packing ----------------
__global__ __launch_bounds__(256)
void prep(const float* __restrict__ x,
          const float* __restrict__ wq, const float* __restrict__ wk,
          const float* __restrict__ wv, const float* __restrict__ wo,
          const float* __restrict__ w2,
          const float* __restrict__ bq, const float* __restrict__ bk,
          const float* __restrict__ bv,
          bf16_t* __restrict__ xb, bf16_t* __restrict__ wqkv,
          bf16_t* __restrict__ wob, bf16_t* __restrict__ w2b,
          float* __restrict__ bqkv)
{
    const int seg = blockIdx.y;
    const int idx = blockIdx.x * 256 + threadIdx.x;   // float4 index
    if (seg == 0) {                      // xb: 8192*768
        if (idx >= 1572864) return;
        const float4 f = ((const float4*)x)[idx];
        bf16x4 o = {(bf16_t)f.x, (bf16_t)f.y, (bf16_t)f.z, (bf16_t)f.w};
        ((bf16x4*)xb)[idx] = o;
    } else if (seg == 1) {               // wqkv: 3*768*768 packed q|k|v (q scaled 1/8)
        if (idx >= 442368) return;
        const int e = idx * 4;
        float4 f = (e < 589824) ? ((const float4*)wq)[idx]
                 : (e < 1179648) ? ((const float4*)wk)[idx - 147456]
                                 : ((const float4*)wv)[idx - 294912];
        if (e < 589824) { f.x *= 0.125f; f.y *= 0.125f; f.z *= 0.125f; f.w *= 0.125f; }
        bf16x4 o = {(bf16_t)f.x, (bf16_t)f.y, (bf16_t)f.z, (bf16_t)f.w};
        ((bf16x4*)wqkv)[idx] = o;
    } else if (seg == 2) {               // wob: 768*768
        if (idx >= 147456) return;
        const float4 f = ((const float4*)wo)[idx];
        bf16x4 o = {(bf16_t)f.x, (bf16_t)f.y, (bf16_t)f.z, (bf16_t)f.w};
        ((bf16x4*)wob)[idx] = o;
    } else if (seg == 3) {               // w2b: 768*3072
        if (idx >= 589824) return;
        const float4 f = ((const float4*)w2)[idx];
        bf16x4 o = {(bf16_t)f.x, (bf16_t)f.y, (bf16_t)f.z, (bf16_t)f.w};
        ((bf16x4*)w2b)[idx] = o;
    } else {                             // bqkv: 2304 fp32 concat (bq scaled 1/8)
        if (idx >= 576) return;
        const int e = idx * 4;
        float4 f = (e < 768) ? ((const float4*)bq)[idx]
                 : (e < 1536) ? ((const float4*)bk)[idx - 192]
                              : ((const float4*)bv)[idx - 384];
        if (e < 768) { f.x *= 0.125f; f.y *= 0.125f; f.z *= 0.125f; f.w *= 0.125f; }
        ((float4*)bqkv)[idx] = f;
    }
}

// ---------------- GEMM (all-bf16): C = A[M,K]@W[N,K]^T + bias ----------------
// 128x128 tile, BK=32, 2-phase double-buffered LDS (stage t+1 || MFMA t),
// global_load_lds staging, XCD-chunked block swizzle. gridDim.z = split-K.
template<typename TC>
__global__ __launch_bounds__(256)
void gemm_bb(const bf16_t* __restrict__ A, const bf16_t* __restrict__ W,
             const float* __restrict__ bias, TC* __restrict__ C,
             int kPer, int lda, int ldw, int ldc, int splitStride)
{
    __shared__ __align__(16) bf16_t As[2][4096];   // [128][32] x2
    __shared__ __align__(16) bf16_t Bs[2][4096];
    const int tid  = threadIdx.x;
    const int wave = tid >> 6;
    const int lane = tid & 63;
    const int wm = (wave >> 1) * 64;
    const int wn = (wave & 1) * 64;

    // XCD-chunked swizzle over (x,y); nwg_xy % 8 == 0 for all call sites
    const int nwg  = gridDim.x * gridDim.y;
    const int flat = blockIdx.y * gridDim.x + blockIdx.x;
    const int swz  = (flat & 7) * (nwg >> 3) + (flat >> 3);
    const int bm = (swz / gridDim.x) * 128;
    const int bn = (swz % gridDim.x) * 128;

    const int fr = lane & 15;
    const int fk = (lane >> 4) * 8;

    const int kBeg = blockIdx.z * kPer;
    const int kEnd = kBeg + kPer;
    C += (size_t)blockIdx.z * splitStride;

    const int srow = tid >> 2;          // 0..63
    const int scol = (tid & 3) * 8;     // 0,8,16,24

    floatx4 acc[4][4] = {};

    const bf16_t* gA = A + (size_t)(bm + srow) * lda + scol;
    const bf16_t* gB = W + (size_t)(bn + srow) * ldw + scol;

#define STAGE(buf, kk)                                              \
    {   const bf16_t* ga = gA + (kk);                               \
        const bf16_t* gb = gB + (kk);                               \
        gload16(ga,                    &As[buf][tid * 8]);          \
        gload16(ga + (size_t)64 * lda, &As[buf][tid * 8 + 2048]);   \
        gload16(gb,                    &Bs[buf][tid * 8]);          \
        gload16(gb + (size_t)64 * ldw, &Bs[buf][tid * 8 + 2048]);   \
    }

    STAGE(0, kBeg);
    __syncthreads();                 // compiler drains vmcnt before barrier

    int cur = 0;
    for (int k0 = kBeg; k0 < kEnd; k0 += 32) {
        if (k0 + 32 < kEnd) STAGE(cur ^ 1, k0 + 32);

        bf16x8 fa[4], fb[4];
        #pragma unroll
        for (int i = 0; i < 4; ++i) {
            fa[i] = *(const bf16x8*)&As[cur][(wm + i * 16 + fr) * 32 + fk];
            fb[i] = *(const bf16x8*)&Bs[cur][(wn + i * 16 + fr) * 32 + fk];
        }
        #pragma unroll
        for (int mi = 0; mi < 4; ++mi)
            #pragma unroll
            for (int ni = 0; ni < 4; ++ni)
                acc[mi][ni] = __builtin_amdgcn_mfma_f32_16x16x32_bf16(
                    fa[mi], fb[ni], acc[mi][ni], 0, 0, 0);

        __syncthreads();             // next tile staged; prev reads done
        cur ^= 1;
    }
#undef STAGE

    const int fg = (lane >> 4) * 4;
    const bool addb = (blockIdx.z == 0);
    #pragma unroll
    for (int mi = 0; mi < 4; ++mi) {
        #pragma unroll
        for (int ni = 0; ni < 4; ++ni) {
            const int col = bn + wn + ni * 16 + fr;
            const float bv = addb ? bias[col] : 0.f;
            #pragma unroll
            for (int r = 0; r < 4; ++r) {
                const int row = bm + wm + mi * 16 + fg + r;
                C[(size_t)row * ldc + col] = (TC)(acc[mi][ni][r] + bv);
            }
        }
    }
}

// ---------------- MFMA flash attention v3 ----------------
// v2 + XCD-chunked swizzle + register prefetch of next KV tile (T14).
__global__ __launch_bounds__(256)
void attn_mfma(const bf16_t* __restrict__ qkv, const int* __restrict__ mask,
               bf16_t* __restrict__ ctx)
{
    __shared__ bf16_t Ks[64][72];     // K[key][d], 144B rows
    __shared__ bf16_t Vt[80][72];     // V^T[d][key]; row64=ones, 65..79=0
    __shared__ float  mb_s[64];
    __shared__ bf16_t Pl[4][32][72];  // per-wave P[q][key]

    // 1D grid 768: swizzle so the 16 q-blocks of one (b,h) share an XCD
    const int flat = blockIdx.x;
    const int swz  = (flat & 7) * 96 + (flat >> 3);
    const int bh = swz >> 4;
    const int b = bh / 12, h = bh % 12;
    const int tid  = threadIdx.x;
    const int wave = tid >> 6;
    const int lane = tid & 63;
    const int g    = lane >> 4;
    const int fr   = lane & 15;
    const int qbase = (swz & 15) * 128 + wave * 32;

    for (int idx = tid; idx < 16 * 72; idx += 256) {
        const int rr = idx / 72, cc = idx % 72;
        Vt[64 + rr][cc] = (bf16_t)(rr == 0 ? 1.f : 0.f);
    }

    // Q fragments (already scaled by 1/8 via prep)
    bf16x8 qf[2][2];
    #pragma unroll
    for (int qt = 0; qt < 2; ++qt)
        #pragma unroll
        for (int s = 0; s < 2; ++s) {
            const size_t tok = (size_t)(b * 2048 + qbase + qt * 16 + fr);
            qf[qt][s] = *(const bf16x8*)(qkv + tok * 2304 + h * 64 + s * 32 + g * 8);
        }

    floatx4 o[2][4] = {};
    floatx4 oe[2] = {};

    const int skey = tid & 63;
    const int sgrp = tid >> 6;

    // prefetch registers (tile kt staged in regs before its LDS write)
    bf16x8 rk0, rk1, rv0, rv1;
    float  rmb;
    {
        const size_t ktok = (size_t)(b * 2048 + skey) * 2304 + h * 64;
        rk0 = *(const bf16x8*)(qkv + ktok + 768 + sgrp * 16);
        rk1 = *(const bf16x8*)(qkv + ktok + 768 + sgrp * 16 + 8);
        rv0 = *(const bf16x8*)(qkv + ktok + 1536 + sgrp * 16);
        rv1 = *(const bf16x8*)(qkv + ktok + 1536 + sgrp * 16 + 8);
        rmb = (mask[b * 2048 + skey] == 0) ? -1e9f : 0.f;
    }

    for (int kt = 0; kt < 32; ++kt) {
        __syncthreads();   // previous compute done reading LDS
        // write staged regs -> LDS
        *(bf16x8*)&Ks[skey][sgrp * 16]     = rk0;
        *(bf16x8*)&Ks[skey][sgrp * 16 + 8] = rk1;
        #pragma unroll
        for (int j = 0; j < 8; ++j) {
            Vt[sgrp * 16 + j][skey]     = rv0[j];
            Vt[sgrp * 16 + 8 + j][skey] = rv1[j];
        }
        if (tid < 64) mb_s[tid] = rmb;
        __syncthreads();   // tile ready

        // issue next tile's loads; latency hides under compute below
        if (kt + 1 < 32) {
            const size_t ktok = (size_t)(b * 2048 + (kt + 1) * 64 + skey) * 2304 + h * 64;
            rk0 = *(const bf16x8*)(qkv + ktok + 768 + sgrp * 16);
            rk1 = *(const bf16x8*)(qkv + ktok + 768 + sgrp * 16 + 8);
            rv0 = *(const bf16x8*)(qkv + ktok + 1536 + sgrp * 16);
            rv1 = *(const bf16x8*)(qkv + ktok + 1536 + sgrp * 16 + 8);
            rmb = (mask[b * 2048 + (kt + 1) * 64 + skey] == 0) ? -1e9f : 0.f;
        }

        // ---- QK^T transposed: S^T = mfma(K, Q) ----
        floatx4 st_[2][4] = {};
        #pragma unroll
        for (int s = 0; s < 2; ++s) {
            bf16x8 kf[4];
            #pragma unroll
            for (int ct = 0; ct < 4; ++ct)
                kf[ct] = *(const bf16x8*)&Ks[ct * 16 + fr][s * 32 + g * 8];
            #pragma unroll
            for (int qt = 0; qt < 2; ++qt)
                #pragma unroll
                for (int ct = 0; ct < 4; ++ct)
                    st_[qt][ct] = __builtin_amdgcn_mfma_f32_16x16x32_bf16(
                        kf[ct], qf[qt][s], st_[qt][ct], 0, 0, 0);
        }

        // ---- softmax (no max): p = exp2(s*log2e + mb) ----
        #pragma unroll
        for (int qt = 0; qt < 2; ++qt) {
            #pragma unroll
            for (int ct = 0; ct < 4; ++ct) {
                const float4 mb4 = *(const float4*)&mb_s[ct * 16 + g * 4];
                const float mbr[4] = { mb4.x, mb4.y, mb4.z, mb4.w };
                bf16x4 pw;
                #pragma unroll
                for (int r = 0; r < 4; ++r)
                    pw[r] = (bf16_t)__builtin_amdgcn_exp2f(
                        fmaf(st_[qt][ct][r], LOG2E, mbr[r]));
                *(bf16x4*)&Pl[wave][qt * 16 + fr][ct * 16 + g * 4] = pw;
            }
        }

        // ---- PV + ones-column l (wave-local Pl) ----
        #pragma unroll
        for (int st2 = 0; st2 < 2; ++st2) {
            bf16x8 pf[2];
            #pragma unroll
            for (int qt = 0; qt < 2; ++qt)
                pf[qt] = *(const bf16x8*)&Pl[wave][qt * 16 + fr][st2 * 32 + g * 8];
            #pragma unroll
            for (int dt = 0; dt < 4; ++dt) {
                const bf16x8 vf = *(const bf16x8*)&Vt[dt * 16 + fr][st2 * 32 + g * 8];
                #pragma unroll
                for (int qt = 0; qt < 2; ++qt)
                    o[qt][dt] = __builtin_amdgcn_mfma_f32_16x16x32_bf16(
                        pf[qt], vf, o[qt][dt], 0, 0, 0);
            }
            const bf16x8 vo = *(const bf16x8*)&Vt[64 + fr][st2 * 32 + g * 8];
            #pragma unroll
            for (int qt = 0; qt < 2; ++qt)
                oe[qt] = __builtin_amdgcn_mfma_f32_16x16x32_bf16(
                    pf[qt], vo, oe[qt], 0, 0, 0);
        }
    }

    #pragma unroll
    for (int qt = 0; qt < 2; ++qt) {
        float inv[4];
        #pragma unroll
        for (int r = 0; r < 4; ++r) {
            const float lv = __shfl(oe[qt][r], (lane & 48), 64);
            inv[r] = 1.f / lv;
        }
        #pragma unroll
        for (int dt = 0; dt < 4; ++dt)
            #pragma unroll
            for (int r = 0; r < 4; ++r) {
                const size_t row = (size_t)(b * 2048 + qbase + qt * 16 + g * 4 + r);
                ctx[row * 768 + h * 64 + dt * 16 + fr] = (bf16_t)(o[qt][dt][r] * inv[r]);
            }
    }
}

// ---------------- fused residual + LayerNorm (float4, 1 wave/row) ----------------
__global__ __launch_bounds__(256)
void ln_fuse(const float* __restrict__ xin, const float* __restrict__ proj,
             const float* __restrict__ proj2,
             const float* __restrict__ g, const float* __restrict__ be,
             float* __restrict__ out,
             const float* __restrict__ theta, float* __restrict__ meas)
{
    const int wave = threadIdx.x >> 6;
    const int lane = threadIdx.x & 63;
    const int row  = blockIdx.x * 4 + wave;
    const size_t base = (size_t)row * 768;

    float4 v[3];
    float s1 = 0.f, s2 = 0.f;
    #pragma unroll
    for (int i = 0; i < 3; ++i) {
        const int c4 = lane + i * 64;
        const float4 a  = ((const float4*)(xin  + base))[c4];
        const float4 p  = ((const float4*)(proj + base))[c4];
        const float4 p2 = ((const float4*)(proj2 + base))[c4];
        v[i].x = a.x + p.x + p2.x;
        v[i].y = a.y + p.y + p2.y;
        v[i].z = a.z + p.z + p2.z;
        v[i].w = a.w + p.w + p2.w;
        s1 += v[i].x + v[i].y + v[i].z + v[i].w;
        s2 += v[i].x*v[i].x + v[i].y*v[i].y + v[i].z*v[i].z + v[i].w*v[i].w;
    }
    #pragma unroll
    for (int mk = 32; mk >= 1; mk >>= 1) {
        s1 += __shfl_xor(s1, mk, 64);
        s2 += __shfl_xor(s2, mk, 64);
    }
    const float mu   = s1 * (1.f / 768.f);
    const float var  = s2 * (1.f / 768.f) - mu * mu;
    const float rinv = rsqrtf(var + 1e-5f);

    #pragma unroll
    for (int i = 0; i < 3; ++i) {
        const int c4 = lane + i * 64;
        const float4 gg = ((const float4*)g)[c4];
        const float4 bb = ((const float4*)be)[c4];
        float4 o;
        o.x = (v[i].x - mu) * rinv * gg.x + bb.x;
        o.y = (v[i].y - mu) * rinv * gg.y + bb.y;
        o.z = (v[i].z - mu) * rinv * gg.z + bb.z;
        o.w = (v[i].w - mu) * rinv * gg.w + bb.w;
        ((float4*)(out + base))[c4] = o;
        if (i == 0 && meas != nullptr && lane < 2) {
            meas[row * 8 + lane * 4 + 0] = cosf(o.x + theta[lane * 4 + 0]);
            meas[row * 8 + lane * 4 + 1] = cosf(o.y + theta[lane * 4 + 1]);
            meas[row * 8 + lane * 4 + 2] = cosf(o.z + theta[lane * 4 + 2]);
            meas[row * 8 + lane * 4 + 3] = cosf(o.w + theta[lane * 4 + 3]);
        }
    }
}

// ---------------- quantum FFN stage 1 ----------------
__global__ __launch_bounds__(256)
void ffn1(const float* __restrict__ meas, const float* __restrict__ w1,
          const float* __restrict__ b1, bf16_t* __restrict__ h)
{
    const int row = blockIdx.x;
    __shared__ float ms[8];
    if (threadIdx.x < 8) ms[threadIdx.x] = meas[row * 8 + threadIdx.x];
    __syncthreads();
    #pragma unroll
    for (int i = 0; i < 12; ++i) {
        const int f = threadIdx.x + i * 256;
        const float4 wa = *(const float4*)(w1 + f * 8);
        const float4 wb = *(const float4*)(w1 + f * 8 + 4);
        float v = b1[f];
        v += ms[0]*wa.x + ms[1]*wa.y + ms[2]*wa.z + ms[3]*wa.w;
        v += ms[4]*wb.x + ms[5]*wb.y + ms[6]*wb.z + ms[7]*wb.w;
        h[(size_t)row * 3072 + f] = (bf16_t)fmaxf(v, 0.f);
    }
}

extern "C" void kernel_launch(void* const* d_in, const int* in_sizes, int n_in,
                              void* d_out, int out_size, void* d_ws, size_t ws_size,
                              hipStream_t stream)
{
    const float* x     = (const float*)d_in[0];
    const int*   mask  = (const int*)d_in[1];
    const float* wq    = (const float*)d_in[2];
    const float* bq    = (const float*)d_in[3];
    const float* wk    = (const float*)d_in[4];
    const float* bk    = (const float*)d_in[5];
    const float* wv    = (const float*)d_in[6];
    const float* bv    = (const float*)d_in[7];
    const float* wo    = (const float*)d_in[8];
    const float* bo    = (const float*)d_in[9];
    const float* g1    = (const float*)d_in[10];
    const float* be1   = (const float*)d_in[11];
    const float* g2    = (const float*)d_in[12];
    const float* be2   = (const float*)d_in[13];
    const float* theta = (const float*)d_in[14];
    const float* w1    = (const float*)d_in[15];
    const float* b1    = (const float*)d_in[16];
    const float* w2    = (const float*)d_in[17];
    const float* b2    = (const float*)d_in[18];
    float* out = (float*)d_out;

    char* ws = (char*)d_ws;
    bf16_t* qkv    = (bf16_t*)(ws + 0);           // 37748736; reused by ffnp after attn
    bf16_t* ctx    = (bf16_t*)(ws + 37748736);    // 12582912
    float*  attnp  = (float*)(ws + 50331648);     // 2 x 25165824; reused by h after ln1
    float*  y      = (float*)(ws + 100663296);    // 25165824
    float*  meas   = (float*)(ws + 125829120);    // 262144
    bf16_t* xb     = (bf16_t*)(ws + 126091264);   // 12582912
    bf16_t* wqkv   = (bf16_t*)(ws + 138674176);   // 3538944
    bf16_t* wob    = (bf16_t*)(ws + 142213120);   // 1179648
    bf16_t* w2b    = (bf16_t*)(ws + 143392768);   // 4718592
    float*  bqkv   = (float*)(ws + 148111360);    // 9216
    float*  ffnp   = (float*)(ws + 0);            // 2 x 25165824 (aliases qkv+ctx)
    bf16_t* h      = (bf16_t*)(ws + 50331648);    // 50331648 (aliases attnp)

    const dim3 blk(256);

    prep<<<dim3(6144, 5), blk, 0, stream>>>(x, wq, wk, wv, wo, w2, bq, bk, bv,
                                            xb, wqkv, wob, w2b, bqkv);

    // qkv = xb @ wqkv^T + bqkv   [8192,2304] bf16 (q section pre-scaled by 1/8)
    gemm_bb<bf16_t><<<dim3(18, 64, 1), blk, 0, stream>>>(
        xb, wqkv, bqkv, qkv, 768, 768, 768, 2304, 0);

    attn_mfma<<<dim3(768), blk, 0, stream>>>(qkv, mask, ctx);

    // attnp = ctx @ wob^T + bo   split-K=2 fp32 partials
    gemm_bb<float><<<dim3(6, 64, 2), blk, 0, stream>>>(
        ctx, wob, bo, attnp, 384, 768, 768, 768, 6291456);

    ln_fuse<<<dim3(2048), blk, 0, stream>>>(x, attnp, attnp + 6291456,
                                            g1, be1, y, theta, meas);

    ffn1<<<dim3(8192), blk, 0, stream>>>(meas, w1, b1, h);

    // ffnp = h @ w2b^T + b2      split-K=2 fp32 partials
    gemm_bb<float><<<dim3(6, 64, 2), blk, 0, stream>>>(
        h, w2b, b2, ffnp, 1536, 3072, 3072, 768, 6291456);

    ln_fuse<<<dim3(2048), blk, 0, stream>>>(y, ffnp, ffnp + 6291456,
                                            g2, be2, out, nullptr, nullptr);
}